// Round 3
// baseline (2044.525 us; speedup 1.0000x reference)
//
#include <hip/hip_runtime.h>

#define NROWS 32768   // B*T = 16*2048
#define DIM 256
#define KCODES 1024
#define NLEV 4
#define TD 16         // d-tile for codebook staging

// ============ codebook squared norms (bit-identical to passing rounds) ============
__global__ __launch_bounds__(256) void k_bnorm(const float* __restrict__ cb,
                                               float* __restrict__ bv) {
  int r = blockIdx.x * blockDim.x + threadIdx.x;  // 0..4095
  if (r >= NLEV * KCODES) return;
  const float4* p = reinterpret_cast<const float4*>(cb + (size_t)r * DIM);
  float s0 = 0.f, s1 = 0.f, s2 = 0.f, s3 = 0.f;
  for (int g = 0; g < DIM / 4; ++g) {
    float4 v = p[g];
    s0 += v.x * v.x; s1 += v.y * v.y; s2 += v.z * v.z; s3 += v.w * v.w;
  }
  bv[r] = (s0 + s1) + (s2 + s3);
}

// ============ codebook transpose: cb[l][code][d] -> cbT[l][d][code] ============
// 256 blocks, 16 code-rows each (one level per 64 blocks).
__global__ __launch_bounds__(256) void k_tcb(const float* __restrict__ cb,
                                             float* __restrict__ cbT) {
  __shared__ __align__(16) float sh[16][272];
  const int tid = threadIdx.x;
  const int lvl = blockIdx.x >> 6;
  const int c0 = (blockIdx.x & 63) * 16;
  // phase A: coalesced row-major read
  {
    const int cr = tid >> 4;         // 0..15 local code
    const int l16 = tid & 15;        // d-sixteenth
    const float4* p = reinterpret_cast<const float4*>(
        cb + ((size_t)lvl * KCODES + c0 + cr) * DIM + l16 * 16);
    #pragma unroll
    for (int j = 0; j < 4; ++j) {
      float4 v = p[j];
      sh[cr][l16 * 16 + 4 * j + 0] = v.x;
      sh[cr][l16 * 16 + 4 * j + 1] = v.y;
      sh[cr][l16 * 16 + 4 * j + 2] = v.z;
      sh[cr][l16 * 16 + 4 * j + 3] = v.w;
    }
  }
  __syncthreads();
  // phase B: thread t = d, write 16 consecutive codes
  {
    float w[16];
    #pragma unroll
    for (int r = 0; r < 16; ++r) w[r] = sh[r][tid];
    float4* o = reinterpret_cast<float4*>(
        cbT + (size_t)lvl * (DIM * KCODES) + (size_t)tid * KCODES + c0);
    o[0] = make_float4(w[0], w[1], w[2], w[3]);
    o[1] = make_float4(w[4], w[5], w[6], w[7]);
    o[2] = make_float4(w[8], w[9], w[10], w[11]);
    o[3] = make_float4(w[12], w[13], w[14], w[15]);
  }
}

// ============ x -> residT (transpose) + rowsq ============
// 2048 blocks x 16 rows.
__global__ __launch_bounds__(256) void k_prep(const float* __restrict__ x,
                                              float* __restrict__ residT,
                                              float* __restrict__ rowsq) {
  __shared__ __align__(16) float sh[16][272];
  __shared__ float sred[256];
  const int tid = threadIdx.x;
  const int row0 = blockIdx.x * 16;
  const int rr = tid >> 4;
  const int l16 = tid & 15;
  float e = 0.f;
  {
    const float4* p = reinterpret_cast<const float4*>(
        x + (size_t)(row0 + rr) * DIM + l16 * 16);
    #pragma unroll
    for (int j = 0; j < 4; ++j) {
      float4 v = p[j];
      sh[rr][l16 * 16 + 4 * j + 0] = v.x;
      sh[rr][l16 * 16 + 4 * j + 1] = v.y;
      sh[rr][l16 * 16 + 4 * j + 2] = v.z;
      sh[rr][l16 * 16 + 4 * j + 3] = v.w;
      e += v.x * v.x + v.y * v.y + v.z * v.z + v.w * v.w;
    }
  }
  sred[tid] = e;
  __syncthreads();
  if (tid < 16) {
    float s = 0.f;
    #pragma unroll
    for (int k = 0; k < 16; ++k) s += sred[tid * 16 + k];
    rowsq[row0 + tid] = s;
  }
  {
    float w[16];
    #pragma unroll
    for (int r = 0; r < 16; ++r) w[r] = sh[r][tid];
    float4* o = reinterpret_cast<float4*>(residT + (size_t)tid * NROWS + row0);
    o[0] = make_float4(w[0], w[1], w[2], w[3]);
    o[1] = make_float4(w[4], w[5], w[6], w[7]);
    o[2] = make_float4(w[8], w[9], w[10], w[11]);
    o[3] = make_float4(w[12], w[13], w[14], w[15]);
  }
}

// ============ fused distance + argmin, one level ============
// 2048 blocks = 512 row-tiles (low bits) x 4 code-quarters (high bits -> same XCD).
// Block: 4 waves x (16 rows, 256 codes). Per lane-d: 1 ds_read_b128 + 64 FMA;
// R operand via wave-uniform scalar loads from residT. Distances bit-identical
// to the verified kernels (same ascending-d fl-FMA chain, same epilogue).
__global__ __launch_bounds__(256) void k_argmin(const float* __restrict__ residT,
                                                const float* __restrict__ cbT,
                                                const float* __restrict__ bv,
                                                const float* __restrict__ rowsq,
                                                unsigned long long* __restrict__ best) {
  __shared__ __align__(16) float Ct[2][TD * 256];
  const int tid = threadIdx.x;
  const int lane = tid & 63;
  const int wid = __builtin_amdgcn_readfirstlane(tid >> 6);
  const int rt = blockIdx.x & 511;
  const int q = blockIdx.x >> 9;
  const int cbase = q * 256;
  const int rowbase = rt * 64 + wid * 16;

  const float* cbq = cbT + cbase;

  float acc[16][4];
  #pragma unroll
  for (int r = 0; r < 16; ++r)
    #pragma unroll
    for (int j = 0; j < 4; ++j) acc[r][j] = 0.f;

  float4 v0, v1, v2, v3;
  // stage tile 0
  {
    int F0 = tid * 4;
    v0 = *reinterpret_cast<const float4*>(cbq + (size_t)((F0          ) >> 8) * KCODES + ((F0          ) & 255));
    v1 = *reinterpret_cast<const float4*>(cbq + (size_t)((F0 + 1024) >> 8) * KCODES + ((F0 + 1024) & 255));
    v2 = *reinterpret_cast<const float4*>(cbq + (size_t)((F0 + 2048) >> 8) * KCODES + ((F0 + 2048) & 255));
    v3 = *reinterpret_cast<const float4*>(cbq + (size_t)((F0 + 3072) >> 8) * KCODES + ((F0 + 3072) & 255));
    *reinterpret_cast<float4*>(&Ct[0][tid * 4])        = v0;
    *reinterpret_cast<float4*>(&Ct[0][tid * 4 + 1024]) = v1;
    *reinterpret_cast<float4*>(&Ct[0][tid * 4 + 2048]) = v2;
    *reinterpret_cast<float4*>(&Ct[0][tid * 4 + 3072]) = v3;
  }
  __syncthreads();

  #pragma unroll 1
  for (int t = 0; t < DIM / TD; ++t) {
    if (t + 1 < DIM / TD) {
      const int d0 = (t + 1) * TD;
      int F0 = tid * 4;
      v0 = *reinterpret_cast<const float4*>(cbq + (size_t)(d0 + ((F0          ) >> 8)) * KCODES + ((F0          ) & 255));
      v1 = *reinterpret_cast<const float4*>(cbq + (size_t)(d0 + ((F0 + 1024) >> 8)) * KCODES + ((F0 + 1024) & 255));
      v2 = *reinterpret_cast<const float4*>(cbq + (size_t)(d0 + ((F0 + 2048) >> 8)) * KCODES + ((F0 + 2048) & 255));
      v3 = *reinterpret_cast<const float4*>(cbq + (size_t)(d0 + ((F0 + 3072) >> 8)) * KCODES + ((F0 + 3072) & 255));
    }
    const float* ct = &Ct[t & 1][0];
    #pragma unroll
    for (int dd = 0; dd < TD; ++dd) {
      const int d = t * TD + dd;
      const float* rtp = residT + (size_t)d * NROWS + rowbase;  // wave-uniform
      float4 cv = *reinterpret_cast<const float4*>(ct + dd * 256 + lane * 4);
      #pragma unroll
      for (int r = 0; r < 16; ++r) {
        float rv = rtp[r];  // scalar (SGPR) load
        acc[r][0] += rv * cv.x;
        acc[r][1] += rv * cv.y;
        acc[r][2] += rv * cv.z;
        acc[r][3] += rv * cv.w;
      }
    }
    if (t + 1 < DIM / TD) {
      const int b = (t + 1) & 1;
      *reinterpret_cast<float4*>(&Ct[b][tid * 4])        = v0;
      *reinterpret_cast<float4*>(&Ct[b][tid * 4 + 1024]) = v1;
      *reinterpret_cast<float4*>(&Ct[b][tid * 4 + 2048]) = v2;
      *reinterpret_cast<float4*>(&Ct[b][tid * 4 + 3072]) = v3;
    }
    __syncthreads();
  }

  // epilogue: dd = fl(fl(A+B) - 2*dot), u64 (dist,idx) min over 64 lanes
  const float4 bvv = *reinterpret_cast<const float4*>(bv + cbase + lane * 4);
  const int code0 = cbase + lane * 4;
  #pragma unroll
  for (int r = 0; r < 16; ++r) {
    const float a = rowsq[rowbase + r];  // uniform; whole-ulp shifts are argmin-invariant
    float t0 = a + bvv.x; float d0v = t0 - 2.0f * acc[r][0];
    float t1 = a + bvv.y; float d1v = t1 - 2.0f * acc[r][1];
    float t2 = a + bvv.z; float d2v = t2 - 2.0f * acc[r][2];
    float t3 = a + bvv.w; float d3v = t3 - 2.0f * acc[r][3];
    unsigned long long u0 = ((unsigned long long)__float_as_uint(d0v) << 32) | (unsigned)(code0 + 0);
    unsigned long long u1 = ((unsigned long long)__float_as_uint(d1v) << 32) | (unsigned)(code0 + 1);
    unsigned long long u2 = ((unsigned long long)__float_as_uint(d2v) << 32) | (unsigned)(code0 + 2);
    unsigned long long u3 = ((unsigned long long)__float_as_uint(d3v) << 32) | (unsigned)(code0 + 3);
    unsigned long long u = u0 < u1 ? u0 : u1;
    u = u2 < u ? u2 : u;
    u = u3 < u ? u3 : u;
    #pragma unroll
    for (int m = 1; m < 64; m <<= 1) {
      unsigned long long o = __shfl_xor(u, m);
      u = (o < u) ? o : u;
    }
    if (lane == 0) atomicMin(best + rowbase + r, u);
  }
}

// ============ residual update (in T layout) + quant accum + losses ============
// 2048 blocks x 16 rows.
__global__ __launch_bounds__(256) void k_update(float* __restrict__ residT,
                                                const float* __restrict__ cb,
                                                const unsigned long long* __restrict__ best,
                                                float* __restrict__ tq,
                                                float* __restrict__ fidx,
                                                float* __restrict__ part,
                                                float* __restrict__ rowsq,
                                                const float* __restrict__ x,
                                                int lvl) {
  __shared__ __align__(16) float sh[16][272];
  __shared__ float sred[256];
  const int tid = threadIdx.x;
  const int row0 = blockIdx.x * 16;

  // phase A: gather this row-tile from residT (thread t = d)
  {
    const float4* p = reinterpret_cast<const float4*>(residT + (size_t)tid * NROWS + row0);
    float4 a0 = p[0], a1 = p[1], a2 = p[2], a3 = p[3];
    sh[0][tid] = a0.x;  sh[1][tid] = a0.y;  sh[2][tid] = a0.z;  sh[3][tid] = a0.w;
    sh[4][tid] = a1.x;  sh[5][tid] = a1.y;  sh[6][tid] = a1.z;  sh[7][tid] = a1.w;
    sh[8][tid] = a2.x;  sh[9][tid] = a2.y;  sh[10][tid] = a2.z; sh[11][tid] = a2.w;
    sh[12][tid] = a3.x; sh[13][tid] = a3.y; sh[14][tid] = a3.z; sh[15][tid] = a3.w;
  }
  __syncthreads();

  // phase B: row-major compute
  const int rr = tid >> 4;
  const int l16 = tid & 15;
  const int row = row0 + rr;
  const int id = (int)(best[row] & 0xffffffffull);
  float nn[16];
  float e = 0.f;
  {
    const float4* cp = reinterpret_cast<const float4*>(cb + (size_t)id * DIM + l16 * 16);
    const size_t obase = (size_t)row * DIM + l16 * 16;
    float4* tp = reinterpret_cast<float4*>(tq + obase);
    const float4* xp = reinterpret_cast<const float4*>(x + obase);
    #pragma unroll
    for (int j = 0; j < 4; ++j) {
      float4 c = cp[j];
      float r0 = sh[rr][l16 * 16 + 4 * j + 0];
      float r1 = sh[rr][l16 * 16 + 4 * j + 1];
      float r2 = sh[rr][l16 * 16 + 4 * j + 2];
      float r3 = sh[rr][l16 * 16 + 4 * j + 3];
      float n0 = r0 - c.x, n1 = r1 - c.y, n2 = r2 - c.z, n3 = r3 - c.w;
      nn[4 * j + 0] = n0; nn[4 * j + 1] = n1; nn[4 * j + 2] = n2; nn[4 * j + 3] = n3;
      e += (n0 * n0 + n1 * n1) + (n2 * n2 + n3 * n3);
      float4 tv;
      if (lvl == 0) {
        tv = c;
      } else {
        tv = tp[j];
        tv.x += c.x; tv.y += c.y; tv.z += c.z; tv.w += c.w;
      }
      if (lvl == 3) {
        float4 xv = xp[j];
        tv.x = xv.x + (tv.x - xv.x); tv.y = xv.y + (tv.y - xv.y);
        tv.z = xv.z + (tv.z - xv.z); tv.w = xv.w + (tv.w - xv.w);
      }
      tp[j] = tv;
    }
  }
  sred[tid] = e;
  if (l16 == 0) fidx[row] = (float)id;
  __syncthreads();

  // per-row sums -> rowsq (lvl<3) and block loss partial
  __shared__ float rsum[16];
  if (tid < 16) {
    float s = 0.f;
    #pragma unroll
    for (int k = 0; k < 16; ++k) s += sred[tid * 16 + k];
    rsum[tid] = s;
    if (lvl < 3) rowsq[row0 + tid] = s;
  }
  __syncthreads();
  if (tid == 0) {
    float p = 0.f;
    #pragma unroll
    for (int k = 0; k < 16; ++k) p += rsum[k];
    part[blockIdx.x] = p;
  }

  // phase C/D: write new residual back transposed (lvl<3)
  if (lvl < 3) {
    #pragma unroll
    for (int k = 0; k < 16; ++k) sh[rr][l16 * 16 + k] = nn[k];
    __syncthreads();
    float w[16];
    #pragma unroll
    for (int r = 0; r < 16; ++r) w[r] = sh[r][tid];
    float4* o = reinterpret_cast<float4*>(residT + (size_t)tid * NROWS + row0);
    o[0] = make_float4(w[0], w[1], w[2], w[3]);
    o[1] = make_float4(w[4], w[5], w[6], w[7]);
    o[2] = make_float4(w[8], w[9], w[10], w[11]);
    o[3] = make_float4(w[12], w[13], w[14], w[15]);
  }
}

// ============ loss finalize ============
__global__ __launch_bounds__(256) void k_loss(const float* __restrict__ part,
                                              float* __restrict__ out) {
  __shared__ float s[256];
  const int tid = threadIdx.x;
  float means[4];
  for (int l = 0; l < 4; ++l) {
    float sum = 0.f;
    for (int i = tid; i < 2048; i += 256) sum += part[l * 2048 + i];
    s[tid] = sum;
    __syncthreads();
    for (int st = 128; st > 0; st >>= 1) {
      if (tid < st) s[tid] += s[tid + st];
      __syncthreads();
    }
    means[l] = s[0] * (1.0f / 8388608.0f);  // /(N*D), exact pow2
    __syncthreads();
  }
  if (tid == 0) {
    float t = ((means[0] + means[1]) + means[2]) + means[3];
    float loss = t * 0.25f;
    out[0] = loss;
    out[1] = loss;
  }
}

extern "C" void kernel_launch(void* const* d_in, const int* in_sizes, int n_in,
                              void* d_out, int out_size, void* d_ws, size_t ws_size,
                              hipStream_t stream) {
  const float* x  = (const float*)d_in[0];
  const float* cb = (const float*)d_in[1];
  float* out = (float*)d_out;
  float* ws  = (float*)d_ws;

  // ws layout (float units)
  float* residT = ws;                                   // 8388608
  unsigned long long* best4 = (unsigned long long*)(ws + 8388608);  // 131072 u64 = 262144 f
  float* part  = ws + 8388608 + 262144;                 // 4*2048
  float* bv    = ws + 8388608 + 262144 + 8192;          // 4096
  float* rowsq = ws + 8388608 + 262144 + 8192 + 4096;   // 32768
  float* cbT   = ws + 8388608 + 262144 + 8192 + 4096 + 32768;  // 1048576

  float* tq      = out;                    // total_quant accumulates in d_out
  float* lossout = out + 8388608;
  float* fidx    = out + 8388610;

  hipMemsetAsync(best4, 0xFF, (size_t)NLEV * NROWS * 8, stream);
  k_bnorm<<<16, 256, 0, stream>>>(cb, bv);
  k_tcb<<<256, 256, 0, stream>>>(cb, cbT);
  k_prep<<<2048, 256, 0, stream>>>(x, residT, rowsq);

  for (int l = 0; l < NLEV; ++l) {
    const float* cbl  = cb  + (size_t)l * KCODES * DIM;
    const float* cbTl = cbT + (size_t)l * KCODES * DIM;
    k_argmin<<<2048, 256, 0, stream>>>(residT, cbTl, bv + l * KCODES, rowsq,
                                       best4 + (size_t)l * NROWS);
    k_update<<<2048, 256, 0, stream>>>(residT, cbl, best4 + (size_t)l * NROWS,
                                       tq, fidx + (size_t)l * NROWS,
                                       part + l * 2048, rowsq, x, l);
  }

  k_loss<<<1, 256, 0, stream>>>(part, lossout);
}

// Round 4
// 1116.993 us; speedup vs baseline: 1.8304x; 1.8304x over previous
//
#include <hip/hip_runtime.h>

#define NROWS 32768   // B*T = 16*2048
#define DIM 256
#define KCODES 1024
#define NLEV 4
#define DTILE 32      // d-slice per staged tile
#define RTILE 128     // rows per block

// ============ codebook squared norms (bit-identical to passing rounds) ============
__global__ __launch_bounds__(256) void k_bnorm(const float* __restrict__ cb,
                                               float* __restrict__ bv) {
  int r = blockIdx.x * blockDim.x + threadIdx.x;  // 0..4095
  if (r >= NLEV * KCODES) return;
  const float4* p = reinterpret_cast<const float4*>(cb + (size_t)r * DIM);
  float s0 = 0.f, s1 = 0.f, s2 = 0.f, s3 = 0.f;
  for (int g = 0; g < DIM / 4; ++g) {
    float4 v = p[g];
    s0 += v.x * v.x; s1 += v.y * v.y; s2 += v.z * v.z; s3 += v.w * v.w;
  }
  bv[r] = (s0 + s1) + (s2 + s3);
}

// ============ codebook transpose: cb[l][code][d] -> cbT[l][d][code] ============
__global__ __launch_bounds__(256) void k_tcb(const float* __restrict__ cb,
                                             float* __restrict__ cbT) {
  __shared__ __align__(16) float sh[16][272];
  const int tid = threadIdx.x;
  const int lvl = blockIdx.x >> 6;
  const int c0 = (blockIdx.x & 63) * 16;
  {
    const int cr = tid >> 4;
    const int l16 = tid & 15;
    const float4* p = reinterpret_cast<const float4*>(
        cb + ((size_t)lvl * KCODES + c0 + cr) * DIM + l16 * 16);
    #pragma unroll
    for (int j = 0; j < 4; ++j) {
      float4 v = p[j];
      sh[cr][l16 * 16 + 4 * j + 0] = v.x;
      sh[cr][l16 * 16 + 4 * j + 1] = v.y;
      sh[cr][l16 * 16 + 4 * j + 2] = v.z;
      sh[cr][l16 * 16 + 4 * j + 3] = v.w;
    }
  }
  __syncthreads();
  {
    float w[16];
    #pragma unroll
    for (int r = 0; r < 16; ++r) w[r] = sh[r][tid];
    float4* o = reinterpret_cast<float4*>(
        cbT + (size_t)lvl * (DIM * KCODES) + (size_t)tid * KCODES + c0);
    o[0] = make_float4(w[0], w[1], w[2], w[3]);
    o[1] = make_float4(w[4], w[5], w[6], w[7]);
    o[2] = make_float4(w[8], w[9], w[10], w[11]);
    o[3] = make_float4(w[12], w[13], w[14], w[15]);
  }
}

// ============ x -> residT (transpose) + rowsq ============
__global__ __launch_bounds__(256) void k_prep(const float* __restrict__ x,
                                              float* __restrict__ residT,
                                              float* __restrict__ rowsq) {
  __shared__ __align__(16) float sh[16][272];
  __shared__ float sred[256];
  const int tid = threadIdx.x;
  const int row0 = blockIdx.x * 16;
  const int rr = tid >> 4;
  const int l16 = tid & 15;
  float e = 0.f;
  {
    const float4* p = reinterpret_cast<const float4*>(
        x + (size_t)(row0 + rr) * DIM + l16 * 16);
    #pragma unroll
    for (int j = 0; j < 4; ++j) {
      float4 v = p[j];
      sh[rr][l16 * 16 + 4 * j + 0] = v.x;
      sh[rr][l16 * 16 + 4 * j + 1] = v.y;
      sh[rr][l16 * 16 + 4 * j + 2] = v.z;
      sh[rr][l16 * 16 + 4 * j + 3] = v.w;
      e += v.x * v.x + v.y * v.y + v.z * v.z + v.w * v.w;
    }
  }
  sred[tid] = e;
  __syncthreads();
  if (tid < 16) {
    float s = 0.f;
    #pragma unroll
    for (int k = 0; k < 16; ++k) s += sred[tid * 16 + k];
    rowsq[row0 + tid] = s;
  }
  {
    float w[16];
    #pragma unroll
    for (int r = 0; r < 16; ++r) w[r] = sh[r][tid];
    float4* o = reinterpret_cast<float4*>(residT + (size_t)tid * NROWS + row0);
    o[0] = make_float4(w[0], w[1], w[2], w[3]);
    o[1] = make_float4(w[4], w[5], w[6], w[7]);
    o[2] = make_float4(w[8], w[9], w[10], w[11]);
    o[3] = make_float4(w[12], w[13], w[14], w[15]);
  }
}

// ============ fused distance + argmin, one level ============
// 1024 blocks = 256 row-tiles (low bits, 128 rows) x 4 code-quarters (high bits
// -> same-XCD row reuse). Block: 256 thr = 16 tx (codes) x 16 ty (rows).
// Per lane-d: 2 broadcast ds_read_b128 (R) + 4 coalesced global b128 (C,
// 1-deep prefetch) + 128 FMA. R staged linearly (conflict-free) from residT,
// double-buffered. Distances bit-identical to rounds 1-3.
__global__ __launch_bounds__(256, 2) void k_argmin(const float* __restrict__ residT,
                                                   const float* __restrict__ cbT,
                                                   const float* __restrict__ bv,
                                                   const float* __restrict__ rowsq,
                                                   unsigned long long* __restrict__ best) {
  __shared__ __align__(16) float Rt[2][DTILE * RTILE];  // 2 x 16 KB
  const int tid = threadIdx.x;
  const int tx = tid & 15;
  const int ty = tid >> 4;
  const int rt = blockIdx.x & 255;
  const int q = blockIdx.x >> 8;
  const int cbase = q * 256;
  const int row0 = rt * RTILE;

  const float* cbq = cbT + cbase + 4 * tx;

  // stage tile 0 (d = 0..31): linear copy residT[d][row0..row0+127] -> Rt[0]
  float4 sreg0, sreg1, sreg2, sreg3;
  {
    const int f = tid * 4;
    sreg0 = *reinterpret_cast<const float4*>(residT + (size_t)((f) >> 7) * NROWS + row0 + (f & 127));
    sreg1 = *reinterpret_cast<const float4*>(residT + (size_t)((f + 1024) >> 7) * NROWS + row0 + ((f + 1024) & 127));
    sreg2 = *reinterpret_cast<const float4*>(residT + (size_t)((f + 2048) >> 7) * NROWS + row0 + ((f + 2048) & 127));
    sreg3 = *reinterpret_cast<const float4*>(residT + (size_t)((f + 3072) >> 7) * NROWS + row0 + ((f + 3072) & 127));
    *reinterpret_cast<float4*>(&Rt[0][tid * 4])        = sreg0;
    *reinterpret_cast<float4*>(&Rt[0][tid * 4 + 1024]) = sreg1;
    *reinterpret_cast<float4*>(&Rt[0][tid * 4 + 2048]) = sreg2;
    *reinterpret_cast<float4*>(&Rt[0][tid * 4 + 3072]) = sreg3;
  }

  // C prefetch for d = 0
  float4 c0n = *reinterpret_cast<const float4*>(cbq);
  float4 c1n = *reinterpret_cast<const float4*>(cbq + 64);
  float4 c2n = *reinterpret_cast<const float4*>(cbq + 128);
  float4 c3n = *reinterpret_cast<const float4*>(cbq + 192);

  __syncthreads();

  float acc[8][16];
  #pragma unroll
  for (int i = 0; i < 8; ++i)
    #pragma unroll
    for (int j = 0; j < 16; ++j) acc[i][j] = 0.f;

  #pragma unroll 1
  for (int t = 0; t < DIM / DTILE; ++t) {
    // issue next tile's global loads now; consumed after compute
    if (t + 1 < DIM / DTILE) {
      const int f = tid * 4;
      const size_t dB = (size_t)(t + 1) * DTILE;
      sreg0 = *reinterpret_cast<const float4*>(residT + (dB + ((f) >> 7)) * NROWS + row0 + (f & 127));
      sreg1 = *reinterpret_cast<const float4*>(residT + (dB + ((f + 1024) >> 7)) * NROWS + row0 + ((f + 1024) & 127));
      sreg2 = *reinterpret_cast<const float4*>(residT + (dB + ((f + 2048) >> 7)) * NROWS + row0 + ((f + 2048) & 127));
      sreg3 = *reinterpret_cast<const float4*>(residT + (dB + ((f + 3072) >> 7)) * NROWS + row0 + ((f + 3072) & 127));
    }
    const float* rbase = &Rt[t & 1][ty * 8];
    #pragma unroll 4
    for (int dd = 0; dd < DTILE; ++dd) {
      const int d = t * DTILE + dd;
      float4 c0 = c0n, c1 = c1n, c2 = c2n, c3 = c3n;
      if (d + 1 < DIM) {
        const float* cpn = cbq + (size_t)(d + 1) * KCODES;
        c0n = *reinterpret_cast<const float4*>(cpn);
        c1n = *reinterpret_cast<const float4*>(cpn + 64);
        c2n = *reinterpret_cast<const float4*>(cpn + 128);
        c3n = *reinterpret_cast<const float4*>(cpn + 192);
      }
      float4 r0 = *reinterpret_cast<const float4*>(rbase + dd * RTILE);
      float4 r1 = *reinterpret_cast<const float4*>(rbase + dd * RTILE + 4);
      float rr8[8] = {r0.x, r0.y, r0.z, r0.w, r1.x, r1.y, r1.z, r1.w};
      float cc16[16] = {c0.x, c0.y, c0.z, c0.w, c1.x, c1.y, c1.z, c1.w,
                        c2.x, c2.y, c2.z, c2.w, c3.x, c3.y, c3.z, c3.w};
      #pragma unroll
      for (int i = 0; i < 8; ++i)
        #pragma unroll
        for (int j = 0; j < 16; ++j)
          acc[i][j] += rr8[i] * cc16[j];
    }
    if (t + 1 < DIM / DTILE) {
      __syncthreads();  // everyone done reading Rt[(t+1)&1] from iter t-1
      const int b = (t + 1) & 1;
      *reinterpret_cast<float4*>(&Rt[b][tid * 4])        = sreg0;
      *reinterpret_cast<float4*>(&Rt[b][tid * 4 + 1024]) = sreg1;
      *reinterpret_cast<float4*>(&Rt[b][tid * 4 + 2048]) = sreg2;
      *reinterpret_cast<float4*>(&Rt[b][tid * 4 + 3072]) = sreg3;
      __syncthreads();
    }
  }

  // epilogue: dd = fl(fl(A+B) - 2*dot); u64 (dist,idx) min over tx; atomicMin
  const float* bvq = bv + cbase;
  #pragma unroll
  for (int i = 0; i < 8; ++i) {
    const int row = row0 + ty * 8 + i;
    const float a = rowsq[row];
    unsigned long long u = ~0ull;
    #pragma unroll
    for (int j = 0; j < 4; ++j) {
      #pragma unroll
      for (int qq = 0; qq < 4; ++qq) {
        const int cl = 64 * j + 4 * tx + qq;
        float tt = a + bvq[cl];                     // fl(A + B)
        float d2 = tt - 2.0f * acc[i][4 * j + qq];  // one rounding
        unsigned long long pk =
            ((unsigned long long)__float_as_uint(d2) << 32) |
            (unsigned)(cbase + cl);
        u = (pk < u) ? pk : u;
      }
    }
    #pragma unroll
    for (int m = 1; m < 16; m <<= 1) {
      unsigned long long o = __shfl_xor(u, m);
      u = (o < u) ? o : u;
    }
    if (tx == 0) atomicMin(best + row, u);
  }
}

// ============ residual update (T layout) + quant accum + losses ============
__global__ __launch_bounds__(256) void k_update(float* __restrict__ residT,
                                                const float* __restrict__ cb,
                                                const unsigned long long* __restrict__ best,
                                                float* __restrict__ tq,
                                                float* __restrict__ fidx,
                                                float* __restrict__ part,
                                                float* __restrict__ rowsq,
                                                const float* __restrict__ x,
                                                int lvl) {
  __shared__ __align__(16) float sh[16][272];
  __shared__ float sred[256];
  const int tid = threadIdx.x;
  const int row0 = blockIdx.x * 16;

  {
    const float4* p = reinterpret_cast<const float4*>(residT + (size_t)tid * NROWS + row0);
    float4 a0 = p[0], a1 = p[1], a2 = p[2], a3 = p[3];
    sh[0][tid] = a0.x;  sh[1][tid] = a0.y;  sh[2][tid] = a0.z;  sh[3][tid] = a0.w;
    sh[4][tid] = a1.x;  sh[5][tid] = a1.y;  sh[6][tid] = a1.z;  sh[7][tid] = a1.w;
    sh[8][tid] = a2.x;  sh[9][tid] = a2.y;  sh[10][tid] = a2.z; sh[11][tid] = a2.w;
    sh[12][tid] = a3.x; sh[13][tid] = a3.y; sh[14][tid] = a3.z; sh[15][tid] = a3.w;
  }
  __syncthreads();

  const int rr = tid >> 4;
  const int l16 = tid & 15;
  const int row = row0 + rr;
  const int id = (int)(best[row] & 0xffffffffull);
  float nn[16];
  float e = 0.f;
  {
    const float4* cp = reinterpret_cast<const float4*>(cb + (size_t)id * DIM + l16 * 16);
    const size_t obase = (size_t)row * DIM + l16 * 16;
    float4* tp = reinterpret_cast<float4*>(tq + obase);
    const float4* xp = reinterpret_cast<const float4*>(x + obase);
    #pragma unroll
    for (int j = 0; j < 4; ++j) {
      float4 c = cp[j];
      float r0 = sh[rr][l16 * 16 + 4 * j + 0];
      float r1 = sh[rr][l16 * 16 + 4 * j + 1];
      float r2 = sh[rr][l16 * 16 + 4 * j + 2];
      float r3 = sh[rr][l16 * 16 + 4 * j + 3];
      float n0 = r0 - c.x, n1 = r1 - c.y, n2 = r2 - c.z, n3 = r3 - c.w;
      nn[4 * j + 0] = n0; nn[4 * j + 1] = n1; nn[4 * j + 2] = n2; nn[4 * j + 3] = n3;
      e += (n0 * n0 + n1 * n1) + (n2 * n2 + n3 * n3);
      float4 tv;
      if (lvl == 0) {
        tv = c;
      } else {
        tv = tp[j];
        tv.x += c.x; tv.y += c.y; tv.z += c.z; tv.w += c.w;
      }
      if (lvl == 3) {
        float4 xv = xp[j];
        tv.x = xv.x + (tv.x - xv.x); tv.y = xv.y + (tv.y - xv.y);
        tv.z = xv.z + (tv.z - xv.z); tv.w = xv.w + (tv.w - xv.w);
      }
      tp[j] = tv;
    }
  }
  sred[tid] = e;
  if (l16 == 0) fidx[row] = (float)id;
  __syncthreads();

  __shared__ float rsum[16];
  if (tid < 16) {
    float s = 0.f;
    #pragma unroll
    for (int k = 0; k < 16; ++k) s += sred[tid * 16 + k];
    rsum[tid] = s;
    if (lvl < 3) rowsq[row0 + tid] = s;
  }
  __syncthreads();
  if (tid == 0) {
    float p = 0.f;
    #pragma unroll
    for (int k = 0; k < 16; ++k) p += rsum[k];
    part[blockIdx.x] = p;
  }

  if (lvl < 3) {
    #pragma unroll
    for (int k = 0; k < 16; ++k) sh[rr][l16 * 16 + k] = nn[k];
    __syncthreads();
    float w[16];
    #pragma unroll
    for (int r = 0; r < 16; ++r) w[r] = sh[r][tid];
    float4* o = reinterpret_cast<float4*>(residT + (size_t)tid * NROWS + row0);
    o[0] = make_float4(w[0], w[1], w[2], w[3]);
    o[1] = make_float4(w[4], w[5], w[6], w[7]);
    o[2] = make_float4(w[8], w[9], w[10], w[11]);
    o[3] = make_float4(w[12], w[13], w[14], w[15]);
  }
}

// ============ loss finalize ============
__global__ __launch_bounds__(256) void k_loss(const float* __restrict__ part,
                                              float* __restrict__ out) {
  __shared__ float s[256];
  const int tid = threadIdx.x;
  float means[4];
  for (int l = 0; l < 4; ++l) {
    float sum = 0.f;
    for (int i = tid; i < 2048; i += 256) sum += part[l * 2048 + i];
    s[tid] = sum;
    __syncthreads();
    for (int st = 128; st > 0; st >>= 1) {
      if (tid < st) s[tid] += s[tid + st];
      __syncthreads();
    }
    means[l] = s[0] * (1.0f / 8388608.0f);  // /(N*D), exact pow2
    __syncthreads();
  }
  if (tid == 0) {
    float t = ((means[0] + means[1]) + means[2]) + means[3];
    float loss = t * 0.25f;
    out[0] = loss;
    out[1] = loss;
  }
}

extern "C" void kernel_launch(void* const* d_in, const int* in_sizes, int n_in,
                              void* d_out, int out_size, void* d_ws, size_t ws_size,
                              hipStream_t stream) {
  const float* x  = (const float*)d_in[0];
  const float* cb = (const float*)d_in[1];
  float* out = (float*)d_out;
  float* ws  = (float*)d_ws;

  // ws layout (float units)
  float* residT = ws;                                   // 8388608
  unsigned long long* best4 = (unsigned long long*)(ws + 8388608);  // 131072 u64
  float* part  = ws + 8388608 + 262144;                 // 4*2048
  float* bv    = ws + 8388608 + 262144 + 8192;          // 4096
  float* rowsq = ws + 8388608 + 262144 + 8192 + 4096;   // 32768
  float* cbT   = ws + 8388608 + 262144 + 8192 + 4096 + 32768;  // 1048576

  float* tq      = out;                    // total_quant accumulates in d_out
  float* lossout = out + 8388608;
  float* fidx    = out + 8388610;

  hipMemsetAsync(best4, 0xFF, (size_t)NLEV * NROWS * 8, stream);
  k_bnorm<<<16, 256, 0, stream>>>(cb, bv);
  k_tcb<<<256, 256, 0, stream>>>(cb, cbT);
  k_prep<<<2048, 256, 0, stream>>>(x, residT, rowsq);

  for (int l = 0; l < NLEV; ++l) {
    const float* cbl  = cb  + (size_t)l * KCODES * DIM;
    const float* cbTl = cbT + (size_t)l * KCODES * DIM;
    k_argmin<<<1024, 256, 0, stream>>>(residT, cbTl, bv + l * KCODES, rowsq,
                                       best4 + (size_t)l * NROWS);
    k_update<<<2048, 256, 0, stream>>>(residT, cbl, best4 + (size_t)l * NROWS,
                                       tq, fidx + (size_t)l * NROWS,
                                       part + l * 2048, rowsq, x, l);
  }

  k_loss<<<1, 256, 0, stream>>>(part, lossout);
}